// Round 15
// baseline (751.192 us; speedup 1.0000x reference)
//
#include <hip/hip_runtime.h>
#include <hip/hip_bf16.h>

#define NEG_SLOPE 0.2f

typedef __attribute__((ext_vector_type(8))) short bf16x8;
typedef __attribute__((ext_vector_type(4))) float f32x4;

__device__ __forceinline__ float bf2f(unsigned short u) {
    return __uint_as_float((unsigned)u << 16);
}
__device__ __forceinline__ float bflo(unsigned u) { return __uint_as_float(u << 16); }
__device__ __forceinline__ float bfhi(unsigned u) { return __uint_as_float(u & 0xFFFF0000u); }
__device__ __forceinline__ unsigned short f2bf(float f) {
    unsigned b = __float_as_uint(f);
    return (unsigned short)((b + 0x7FFFu + ((b >> 16) & 1u)) >> 16);
}

// ---------- CSR build ----------
__global__ void k_hist(const int* __restrict__ dst, int E, int* __restrict__ deg) {
    int e = blockIdx.x * 256 + threadIdx.x;
    if (e < E) atomicAdd(&deg[dst[e]], 1);
}

__global__ __launch_bounds__(1024) void k_scan_chunk(const int* __restrict__ deg,
                                                     int* __restrict__ start,
                                                     int* __restrict__ csum, int n) {
    __shared__ int wsum[16];
    const int lane = threadIdx.x & 63;
    const int w = threadIdx.x >> 6;
    int i = blockIdx.x * 1024 + (int)threadIdx.x;
    int v = (i < n) ? deg[i] : 0;
    int s = v;
#pragma unroll
    for (int o = 1; o < 64; o <<= 1) {
        int u = __shfl_up(s, o);
        if (lane >= o) s += u;
    }
    if (lane == 63) wsum[w] = s;
    __syncthreads();
    if (w == 0) {
        int ws = (lane < 16) ? wsum[lane] : 0;
#pragma unroll
        for (int o = 1; o < 16; o <<= 1) {
            int u = __shfl_up(ws, o);
            if (lane >= o) ws += u;
        }
        if (lane < 16) wsum[lane] = ws;
    }
    __syncthreads();
    int woff = (w == 0) ? 0 : wsum[w - 1];
    int incl = s + woff;
    if (i < n) start[i] = incl - v;
    if (threadIdx.x == 1023) csum[blockIdx.x] = incl;
}

__global__ void k_scan_top(int* __restrict__ csum, int nch, int* __restrict__ start, int n) {
    int t = threadIdx.x;
    int v = (t < nch) ? csum[t] : 0;
    int s = v;
#pragma unroll
    for (int o = 1; o < 64; o <<= 1) {
        int u = __shfl_up(s, o);
        if (t >= o) s += u;
    }
    if (t < nch) csum[t] = s - v;
    if (t == 63) start[n] = s;
}

__global__ void k_scan_apply(int* __restrict__ start, const int* __restrict__ csum, int n) {
    int i = blockIdx.x * 256 + threadIdx.x;
    if (i < n) start[i] += csum[i >> 10];
}

__global__ void k_fill(const int* __restrict__ src, const int* __restrict__ dst, int E,
                       const int* __restrict__ start, int* __restrict__ cursor,
                       int* __restrict__ perm, int* __restrict__ src_sorted,
                       int* __restrict__ sortpos) {
    int e = blockIdx.x * 256 + threadIdx.x;
    if (e >= E) return;
    int d = dst[e];
    int idx = start[d] + atomicAdd(&cursor[d], 1);
    perm[idx] = e;
    src_sorted[idx] = src[e];
    sortpos[e] = idx;
}

// ---------- self-loop attr: gather-side segment mean, 16 rows in flight ----------
__global__ __launch_bounds__(256) void k_loop_csr(
    const float* __restrict__ eattr, const int* __restrict__ perm,
    const int* __restrict__ start, float* __restrict__ loop_attr, int n) {
    int node = blockIdx.x * 4 + (threadIdx.x >> 6);
    int t = threadIdx.x & 63;
    if (node >= n) return;
    int a = start[node], b = start[node + 1];
    int g = t >> 3, gl = t & 7;
    float4 acc = make_float4(0.f, 0.f, 0.f, 0.f);
    int j = a + g;
    for (; j + 8 < b; j += 16) {
        int e1 = perm[j];
        int e2 = perm[j + 8];
        const float4 v1 = *(const float4*)&eattr[(size_t)e1 * 32 + gl * 4];
        const float4 v2 = *(const float4*)&eattr[(size_t)e2 * 32 + gl * 4];
        acc.x += v1.x + v2.x; acc.y += v1.y + v2.y;
        acc.z += v1.z + v2.z; acc.w += v1.w + v2.w;
    }
    if (j < b) {
        int e = perm[j];
        const float4 v = *(const float4*)&eattr[(size_t)e * 32 + gl * 4];
        acc.x += v.x; acc.y += v.y; acc.z += v.z; acc.w += v.w;
    }
#pragma unroll
    for (int mask = 8; mask <= 32; mask <<= 1) {
        acc.x += __shfl_xor(acc.x, mask);
        acc.y += __shfl_xor(acc.y, mask);
        acc.z += __shfl_xor(acc.z, mask);
        acc.w += __shfl_xor(acc.w, mask);
    }
    if (t < 8) {
        float deg = fmaxf((float)(b - a), 1.f);
        float4 o = make_float4(acc.x / deg, acc.y / deg, acc.z / deg, acc.w / deg);
        *(float4*)&loop_attr[(size_t)node * 32 + gl * 4] = o;
    }
}

// ---------- node transform: bf16 tables only ----------
template <int DIN>
__global__ void k_node_transform(const float* __restrict__ h,
                                 const float* __restrict__ Wl, const float* __restrict__ bl,
                                 const float* __restrict__ Wr, const float* __restrict__ br,
                                 unsigned short* __restrict__ xlb,
                                 unsigned short* __restrict__ xrb, int n) {
    __shared__ float hs[4][DIN];
    int node0 = blockIdx.x * 4;
    int tid = threadIdx.x;
    for (int idx = tid; idx < 4 * DIN; idx += 256) {
        int ln = idx / DIN, k = idx % DIN;
        int node = node0 + ln;
        hs[ln][k] = (node < n) ? h[(long long)node * DIN + k] : 0.f;
    }
    __syncthreads();
    int ln = tid >> 6;
    int j = tid & 63;
    int node = node0 + ln;
    if (node >= n) return;
    float al = bl[j], ar = br[j];
#pragma unroll 8
    for (int k = 0; k < DIN; ++k) {
        float hv = hs[ln][k];
        al += hv * Wl[k * 64 + j];
        ar += hv * Wr[k * 64 + j];
    }
    xlb[(long long)node * 64 + j] = f2bf(al);
    xrb[(long long)node * 64 + j] = f2bf(ar);
}

// ---------- phase A: MFMA edge scores, channel-permuted C layout ----------
// 128 edges/block, 4 waves; wave covers 32 edges (2 tiles of 16).
// A-row m of tile ct maps to channel chmap(ct,m) = (m>>2)*16 + ct*4 + (m&3),
// so lane (lo16,hi4) holds channels hi4*16..hi4*16+15 CONTIGUOUS ->
// xl/xr gathers are 2x16B per edge-table per lane, issued at kernel start
// (no LDS dependency) and hidden under ea staging + MFMA.
__global__ __launch_bounds__(256, 2) void k_edge_score(
    const unsigned short* __restrict__ xlb, const unsigned short* __restrict__ xrb,
    const float* __restrict__ eattr,
    const float* __restrict__ We, const float* __restrict__ att,
    const int* __restrict__ src, const int* __restrict__ dst,
    const int* __restrict__ sortpos, int E,
    float* __restrict__ ex_sorted) {
    __shared__ __align__(16) short ea_frag[4][128][8];  // [k-chunk][edge][8 bf16] = 8 KB

    const int tid = threadIdx.x;
    const int ge0 = blockIdx.x * 128;
    const int w = tid >> 6, l = tid & 63;
    const int lo16 = l & 15, hi4 = l >> 4;

    // ---- early: edge ids + xl/xr gathers (latency hides under staging+MFMA) ----
    int sq[2], dq[2];
#pragma unroll
    for (int et = 0; et < 2; ++et) {
        int ge = ge0 + w * 32 + et * 16 + lo16;
        bool ok = ge < E;
        sq[et] = ok ? src[ge] : 0;
        dq[et] = ok ? dst[ge] : 0;
    }
    uint4 xlg[2][2], xrg[2][2];
#pragma unroll
    for (int et = 0; et < 2; ++et) {
        const size_t lbase = (size_t)sq[et] * 64 + hi4 * 16;
        const size_t rbase = (size_t)dq[et] * 64 + hi4 * 16;
        xlg[et][0] = *(const uint4*)&xlb[lbase];
        xlg[et][1] = *(const uint4*)&xlb[lbase + 8];
        xrg[et][0] = *(const uint4*)&xrb[rbase];
        xrg[et][1] = *(const uint4*)&xrb[rbase + 8];
    }

    // ---- stage ea -> bf16 B-fragments (as R12, verified) ----
    {
        const int e = tid & 127;
        const int c0 = (tid >> 7) * 2;
        const int ge = ge0 + e;
        float4 a = make_float4(0.f, 0.f, 0.f, 0.f), b = a, c = a, d4 = a;
        if (ge < E) {
            const float4* p = (const float4*)(eattr + (size_t)ge * 32 + c0 * 8);
            a = p[0]; b = p[1]; c = p[2]; d4 = p[3];
        }
        bf16x8 lo, hi;
        lo[0] = (short)f2bf(a.x); lo[1] = (short)f2bf(a.y); lo[2] = (short)f2bf(a.z); lo[3] = (short)f2bf(a.w);
        lo[4] = (short)f2bf(b.x); lo[5] = (short)f2bf(b.y); lo[6] = (short)f2bf(b.z); lo[7] = (short)f2bf(b.w);
        hi[0] = (short)f2bf(c.x); hi[1] = (short)f2bf(c.y); hi[2] = (short)f2bf(c.z); hi[3] = (short)f2bf(c.w);
        hi[4] = (short)f2bf(d4.x); hi[5] = (short)f2bf(d4.y); hi[6] = (short)f2bf(d4.z); hi[7] = (short)f2bf(d4.w);
        *(bf16x8*)&ea_frag[c0 + 0][e][0] = lo;
        *(bf16x8*)&ea_frag[c0 + 1][e][0] = hi;
    }

    // ---- A-fragments: permuted channel map (L1-cached scalar loads, once) ----
    bf16x8 afrag[4];
#pragma unroll
    for (int ct = 0; ct < 4; ++ct) {
        const int ch = (lo16 >> 2) * 16 + ct * 4 + (lo16 & 3);  // chmap(ct, lo16)
#pragma unroll
        for (int j = 0; j < 8; ++j) {
            afrag[ct][j] = (short)f2bf(We[(hi4 * 8 + j) * 64 + ch]);
        }
    }
    // att values for this lane's 16 contiguous channels
    float attf[16];
    {
        const float4 a0 = *(const float4*)&att[hi4 * 16 + 0];
        const float4 a1 = *(const float4*)&att[hi4 * 16 + 4];
        const float4 a2 = *(const float4*)&att[hi4 * 16 + 8];
        const float4 a3 = *(const float4*)&att[hi4 * 16 + 12];
        attf[0] = a0.x;  attf[1] = a0.y;  attf[2] = a0.z;  attf[3] = a0.w;
        attf[4] = a1.x;  attf[5] = a1.y;  attf[6] = a1.z;  attf[7] = a1.w;
        attf[8] = a2.x;  attf[9] = a2.y;  attf[10] = a2.z; attf[11] = a2.w;
        attf[12] = a3.x; attf[13] = a3.y; attf[14] = a3.z; attf[15] = a3.w;
    }
    __syncthreads();

    // ---- MFMA: z[64ch x 32edges] per wave ----
    f32x4 acc[2][4];
#pragma unroll
    for (int et = 0; et < 2; ++et) {
        bf16x8 bfrag = *(const bf16x8*)&ea_frag[hi4][w * 32 + et * 16 + lo16][0];
#pragma unroll
        for (int ct = 0; ct < 4; ++ct) {
            f32x4 zero = {0.f, 0.f, 0.f, 0.f};
            acc[et][ct] = __builtin_amdgcn_mfma_f32_16x16x32_bf16(afrag[ct], bfrag, zero, 0, 0, 0);
        }
    }

    // ---- epilogue: contiguous-channel gathers already in regs ----
#pragma unroll
    for (int et = 0; et < 2; ++et) {
        float xlf[16], xrf[16];
#pragma unroll
        for (int h = 0; h < 2; ++h) {
            const uint4 ql = xlg[et][h];
            const uint4 qr = xrg[et][h];
            xlf[h * 8 + 0] = bflo(ql.x); xlf[h * 8 + 1] = bfhi(ql.x);
            xlf[h * 8 + 2] = bflo(ql.y); xlf[h * 8 + 3] = bfhi(ql.y);
            xlf[h * 8 + 4] = bflo(ql.z); xlf[h * 8 + 5] = bfhi(ql.z);
            xlf[h * 8 + 6] = bflo(ql.w); xlf[h * 8 + 7] = bfhi(ql.w);
            xrf[h * 8 + 0] = bflo(qr.x); xrf[h * 8 + 1] = bfhi(qr.x);
            xrf[h * 8 + 2] = bflo(qr.y); xrf[h * 8 + 3] = bfhi(qr.y);
            xrf[h * 8 + 4] = bflo(qr.z); xrf[h * 8 + 5] = bfhi(qr.z);
            xrf[h * 8 + 6] = bflo(qr.w); xrf[h * 8 + 7] = bfhi(qr.w);
        }
        float part = 0.f;
#pragma unroll
        for (int ct = 0; ct < 4; ++ct) {
#pragma unroll
            for (int r = 0; r < 4; ++r) {
                const int i = ct * 4 + r;
                float zz = acc[et][ct][r] + xlf[i] + xrf[i];
                zz = (zz > 0.f) ? zz : NEG_SLOPE * zz;
                part += attf[i] * zz;
            }
        }
        part += __shfl_xor(part, 16);
        part += __shfl_xor(part, 32);
        if (l < 16) {
            int ge = ge0 + w * 32 + et * 16 + l;
            if (ge < E) ex_sorted[sortpos[ge]] = __expf(part);
        }
    }
}

// ---------- phase B: gather-side aggregation + in-kernel self-loop score ----------
template <bool FINAL>
__global__ __launch_bounds__(256, 2) void k_node_aggr(
    const unsigned short* __restrict__ xlb, const unsigned short* __restrict__ xrb,
    const float* __restrict__ loop_attr,
    const float* __restrict__ We, const float* __restrict__ att,
    const int* __restrict__ start,
    const int* __restrict__ src_sorted, const float* __restrict__ ex_sorted,
    const float* __restrict__ bias,
    const float* __restrict__ Wc, const float* __restrict__ bc,
    float* __restrict__ hout, int n) {
    __shared__ float la_s[4][32];
    const int ln = threadIdx.x >> 6;
    const int node = blockIdx.x * 4 + ln;
    const int t = threadIdx.x & 63;

    if (threadIdx.x < 128) {
        int nn = blockIdx.x * 4 + (threadIdx.x >> 5);
        int k = threadIdx.x & 31;
        la_s[threadIdx.x >> 5][k] = (nn < n) ? loop_attr[(size_t)nn * 32 + k] : 0.f;
    }
    __syncthreads();
    if (node >= n) return;

    float exl;
    {
        float zl = bf2f(xlb[(size_t)node * 64 + t]) + bf2f(xrb[(size_t)node * 64 + t]);
#pragma unroll 8
        for (int k = 0; k < 32; ++k) zl += We[k * 64 + t] * la_s[ln][k];
        zl = (zl > 0.f) ? zl : NEG_SLOPE * zl;
        float v = att[t] * zl;
#pragma unroll
        for (int mask = 1; mask <= 32; mask <<= 1) v += __shfl_xor(v, mask);
        exl = __expf(v);
    }

    const int g = t >> 3;
    const int c8 = t & 7;
    int a = start[node], b = start[node + 1];

    float acc[8] = {0.f, 0.f, 0.f, 0.f, 0.f, 0.f, 0.f, 0.f};
    float den = 0.f;
    if (g == 0) {
        const uint4 q = *(const uint4*)&xlb[(size_t)node * 64 + c8 * 8];
        acc[0] = exl * bflo(q.x); acc[1] = exl * bfhi(q.x);
        acc[2] = exl * bflo(q.y); acc[3] = exl * bfhi(q.y);
        acc[4] = exl * bflo(q.z); acc[5] = exl * bfhi(q.z);
        acc[6] = exl * bflo(q.w); acc[7] = exl * bfhi(q.w);
        den = exl;
    }
    for (int j = a; j < b; j += 64) {
        int m = b - j; if (m > 64) m = 64;
        int sj = 0; float exj = 0.f;
        if (t < m) { sj = src_sorted[j + t]; exj = ex_sorted[j + t]; }
        for (int i = 0; i < m; i += 16) {
            const int i0 = i + g, i1 = i + 8 + g;
            const int s0 = __shfl(sj, i0); const float e0 = __shfl(exj, i0);
            const int s1 = __shfl(sj, i1); const float e1 = __shfl(exj, i1);
            uint4 q0 = *(const uint4*)&xlb[(size_t)s0 * 64 + c8 * 8];
            uint4 q1 = *(const uint4*)&xlb[(size_t)s1 * 64 + c8 * 8];
            if (i0 < m) {
                acc[0] += e0 * bflo(q0.x); acc[1] += e0 * bfhi(q0.x);
                acc[2] += e0 * bflo(q0.y); acc[3] += e0 * bfhi(q0.y);
                acc[4] += e0 * bflo(q0.z); acc[5] += e0 * bfhi(q0.z);
                acc[6] += e0 * bflo(q0.w); acc[7] += e0 * bfhi(q0.w);
                den += e0;
            }
            if (i1 < m) {
                acc[0] += e1 * bflo(q1.x); acc[1] += e1 * bfhi(q1.x);
                acc[2] += e1 * bflo(q1.y); acc[3] += e1 * bfhi(q1.y);
                acc[4] += e1 * bflo(q1.z); acc[5] += e1 * bfhi(q1.z);
                acc[6] += e1 * bflo(q1.w); acc[7] += e1 * bfhi(q1.w);
                den += e1;
            }
        }
    }
#pragma unroll
    for (int mask = 8; mask <= 32; mask <<= 1) {
#pragma unroll
        for (int r = 0; r < 8; ++r) acc[r] += __shfl_xor(acc[r], mask);
        den += __shfl_xor(den, mask);
    }
    if (!FINAL) {
        if (g == 0) {
            float h[8];
#pragma unroll
            for (int r = 0; r < 8; ++r)
                h[r] = fmaxf(acc[r] / den + bias[c8 * 8 + r], 0.f);
            float4 o0 = make_float4(h[0], h[1], h[2], h[3]);
            float4 o1 = make_float4(h[4], h[5], h[6], h[7]);
            *(float4*)&hout[(size_t)node * 64 + c8 * 8] = o0;
            *(float4*)&hout[(size_t)node * 64 + c8 * 8 + 4] = o1;
        }
    } else {
        float v0 = 0.f, v1 = 0.f;
        if (g == 0) {
#pragma unroll
            for (int r = 0; r < 8; ++r) {
                const int ch = c8 * 8 + r;
                const float h = fmaxf(acc[r] / den + bias[ch], 0.f);
                v0 += h * Wc[ch * 2 + 0];
                v1 += h * Wc[ch * 2 + 1];
            }
        }
#pragma unroll
        for (int mask = 1; mask <= 4; mask <<= 1) {
            v0 += __shfl_xor(v0, mask);
            v1 += __shfl_xor(v1, mask);
        }
        if (t == 0) {
            hout[(size_t)node * 2 + 0] = v0 + bc[0];
            hout[(size_t)node * 2 + 1] = v1 + bc[1];
        }
    }
}

extern "C" void kernel_launch(void* const* d_in, const int* in_sizes, int n_in,
                              void* d_out, int out_size, void* d_ws, size_t ws_size,
                              hipStream_t stream) {
    const float* x     = (const float*)d_in[0];
    const int*   ei    = (const int*)d_in[1];
    const float* eattr = (const float*)d_in[2];
    const float* Wl1 = (const float*)d_in[3];
    const float* bl1 = (const float*)d_in[4];
    const float* Wr1 = (const float*)d_in[5];
    const float* br1 = (const float*)d_in[6];
    const float* We1 = (const float*)d_in[7];
    const float* att1 = (const float*)d_in[8];
    const float* bias1 = (const float*)d_in[9];
    const float* Wl2 = (const float*)d_in[10];
    const float* bl2 = (const float*)d_in[11];
    const float* Wr2 = (const float*)d_in[12];
    const float* br2 = (const float*)d_in[13];
    const float* We2 = (const float*)d_in[14];
    const float* att2 = (const float*)d_in[15];
    const float* bias2 = (const float*)d_in[16];
    const float* Wc = (const float*)d_in[17];
    const float* bc = (const float*)d_in[18];

    const int N = in_sizes[0] / 128;
    const int E = in_sizes[1] / 2;
    const int* src = ei;
    const int* dst = ei + E;

    char* w = (char*)d_ws;
    auto alloc = [&](size_t bytes) {
        char* p = w;
        w += (bytes + 255) & ~(size_t)255;
        return p;
    };
    unsigned short* xlb        = (unsigned short*)alloc((size_t)N * 64 * 2);
    unsigned short* xrb        = (unsigned short*)alloc((size_t)N * 64 * 2);
    float*          hbuf       = (float*)alloc((size_t)N * 64 * 4);
    float*          loop_attr  = (float*)alloc((size_t)N * 32 * 4);
    int*            deg_i      = (int*)alloc((size_t)N * 4);
    int*            start      = (int*)alloc((size_t)(N + 1) * 4);
    int*            cursor     = (int*)alloc((size_t)N * 4);
    int*            csum       = (int*)alloc(256 * 4);
    int*            perm       = (int*)alloc((size_t)E * 4);
    int*            src_sorted = (int*)alloc((size_t)E * 4);
    int*            sortpos    = (int*)alloc((size_t)E * 4);
    float*          ex_sorted  = (float*)alloc((size_t)E * 4);

    const int THREADS = 256;
    const int score_blocks = (E + 127) / 128;
    const int node4_blocks = (N + 3) / 4;
    const int edge_blocks = (E + THREADS - 1) / THREADS;
    const int nchunks = (N + 1023) / 1024;

    // ---- CSR by dst (shared by both layers) ----
    hipMemsetAsync(deg_i, 0, (size_t)N * 4, stream);
    hipMemsetAsync(cursor, 0, (size_t)N * 4, stream);
    k_hist<<<edge_blocks, THREADS, 0, stream>>>(dst, E, deg_i);
    k_scan_chunk<<<nchunks, 1024, 0, stream>>>(deg_i, start, csum, N);
    k_scan_top<<<1, 64, 0, stream>>>(csum, nchunks, start, N);
    k_scan_apply<<<(N + THREADS - 1) / THREADS, THREADS, 0, stream>>>(start, csum, N);
    k_fill<<<edge_blocks, THREADS, 0, stream>>>(src, dst, E, start, cursor,
                                                perm, src_sorted, sortpos);
    k_loop_csr<<<node4_blocks, THREADS, 0, stream>>>(eattr, perm, start, loop_attr, N);

    // ---- layer 1 ----
    k_node_transform<128><<<node4_blocks, THREADS, 0, stream>>>(x, Wl1, bl1, Wr1, br1,
                                                                xlb, xrb, N);
    k_edge_score<<<score_blocks, THREADS, 0, stream>>>(
        xlb, xrb, eattr, We1, att1, src, dst, sortpos, E, ex_sorted);
    k_node_aggr<false><<<node4_blocks, THREADS, 0, stream>>>(
        xlb, xrb, loop_attr, We1, att1, start, src_sorted, ex_sorted,
        bias1, Wc, bc, hbuf, N);

    // ---- layer 2 ----
    k_node_transform<64><<<node4_blocks, THREADS, 0, stream>>>(hbuf, Wl2, bl2, Wr2, br2,
                                                               xlb, xrb, N);
    k_edge_score<<<score_blocks, THREADS, 0, stream>>>(
        xlb, xrb, eattr, We2, att2, src, dst, sortpos, E, ex_sorted);
    k_node_aggr<true><<<node4_blocks, THREADS, 0, stream>>>(
        xlb, xrb, loop_attr, We2, att2, start, src_sorted, ex_sorted,
        bias2, Wc, bc, (float*)d_out, N);
}

// Round 16
// 721.241 us; speedup vs baseline: 1.0415x; 1.0415x over previous
//
#include <hip/hip_runtime.h>
#include <hip/hip_bf16.h>

#define NEG_SLOPE 0.2f

typedef __attribute__((ext_vector_type(8))) short bf16x8;
typedef __attribute__((ext_vector_type(4))) float f32x4;

__device__ __forceinline__ float bf2f(unsigned short u) {
    return __uint_as_float((unsigned)u << 16);
}
__device__ __forceinline__ float bflo(unsigned u) { return __uint_as_float(u << 16); }
__device__ __forceinline__ float bfhi(unsigned u) { return __uint_as_float(u & 0xFFFF0000u); }
__device__ __forceinline__ unsigned short f2bf(float f) {
    unsigned b = __float_as_uint(f);
    return (unsigned short)((b + 0x7FFFu + ((b >> 16) & 1u)) >> 16);
}

// ---------- CSR build ----------
__global__ void k_hist(const int* __restrict__ dst, int E, int* __restrict__ deg) {
    int e = blockIdx.x * 256 + threadIdx.x;
    if (e < E) atomicAdd(&deg[dst[e]], 1);
}

__global__ __launch_bounds__(1024) void k_scan_chunk(const int* __restrict__ deg,
                                                     int* __restrict__ start,
                                                     int* __restrict__ csum, int n) {
    __shared__ int wsum[16];
    const int lane = threadIdx.x & 63;
    const int w = threadIdx.x >> 6;
    int i = blockIdx.x * 1024 + (int)threadIdx.x;
    int v = (i < n) ? deg[i] : 0;
    int s = v;
#pragma unroll
    for (int o = 1; o < 64; o <<= 1) {
        int u = __shfl_up(s, o);
        if (lane >= o) s += u;
    }
    if (lane == 63) wsum[w] = s;
    __syncthreads();
    if (w == 0) {
        int ws = (lane < 16) ? wsum[lane] : 0;
#pragma unroll
        for (int o = 1; o < 16; o <<= 1) {
            int u = __shfl_up(ws, o);
            if (lane >= o) ws += u;
        }
        if (lane < 16) wsum[lane] = ws;
    }
    __syncthreads();
    int woff = (w == 0) ? 0 : wsum[w - 1];
    int incl = s + woff;
    if (i < n) start[i] = incl - v;
    if (threadIdx.x == 1023) csum[blockIdx.x] = incl;
}

__global__ void k_scan_top(int* __restrict__ csum, int nch, int* __restrict__ start, int n) {
    int t = threadIdx.x;
    int v = (t < nch) ? csum[t] : 0;
    int s = v;
#pragma unroll
    for (int o = 1; o < 64; o <<= 1) {
        int u = __shfl_up(s, o);
        if (t >= o) s += u;
    }
    if (t < nch) csum[t] = s - v;
    if (t == 63) start[n] = s;
}

__global__ void k_scan_apply(int* __restrict__ start, const int* __restrict__ csum, int n) {
    int i = blockIdx.x * 256 + threadIdx.x;
    if (i < n) start[i] += csum[i >> 10];
}

// single 8B scattered store per edge: {e, src[e]} packed (halves dirty lines
// vs two 4B scatters to separate arrays — R15's k_fill was 152 MB WRITE)
__global__ void k_fill(const int* __restrict__ src, const int* __restrict__ dst, int E,
                       const int* __restrict__ start, int* __restrict__ cursor,
                       int2* __restrict__ es_sorted, int* __restrict__ sortpos) {
    int e = blockIdx.x * 256 + threadIdx.x;
    if (e >= E) return;
    int d = dst[e];
    int idx = start[d] + atomicAdd(&cursor[d], 1);
    es_sorted[idx] = make_int2(e, src[e]);
    sortpos[e] = idx;
}

// ---------- self-loop attr: gather-side segment mean, 16 rows in flight ----------
__global__ __launch_bounds__(256) void k_loop_csr(
    const float* __restrict__ eattr, const int2* __restrict__ es_sorted,
    const int* __restrict__ start, float* __restrict__ loop_attr, int n) {
    int node = blockIdx.x * 4 + (threadIdx.x >> 6);
    int t = threadIdx.x & 63;
    if (node >= n) return;
    int a = start[node], b = start[node + 1];
    int g = t >> 3, gl = t & 7;
    float4 acc = make_float4(0.f, 0.f, 0.f, 0.f);
    int j = a + g;
    for (; j + 8 < b; j += 16) {
        int e1 = es_sorted[j].x;
        int e2 = es_sorted[j + 8].x;
        const float4 v1 = *(const float4*)&eattr[(size_t)e1 * 32 + gl * 4];
        const float4 v2 = *(const float4*)&eattr[(size_t)e2 * 32 + gl * 4];
        acc.x += v1.x + v2.x; acc.y += v1.y + v2.y;
        acc.z += v1.z + v2.z; acc.w += v1.w + v2.w;
    }
    if (j < b) {
        int e = es_sorted[j].x;
        const float4 v = *(const float4*)&eattr[(size_t)e * 32 + gl * 4];
        acc.x += v.x; acc.y += v.y; acc.z += v.z; acc.w += v.w;
    }
#pragma unroll
    for (int mask = 8; mask <= 32; mask <<= 1) {
        acc.x += __shfl_xor(acc.x, mask);
        acc.y += __shfl_xor(acc.y, mask);
        acc.z += __shfl_xor(acc.z, mask);
        acc.w += __shfl_xor(acc.w, mask);
    }
    if (t < 8) {
        float deg = fmaxf((float)(b - a), 1.f);
        float4 o = make_float4(acc.x / deg, acc.y / deg, acc.z / deg, acc.w / deg);
        *(float4*)&loop_attr[(size_t)node * 32 + gl * 4] = o;
    }
}

// ---------- node transform: bf16 tables only ----------
template <int DIN>
__global__ void k_node_transform(const float* __restrict__ h,
                                 const float* __restrict__ Wl, const float* __restrict__ bl,
                                 const float* __restrict__ Wr, const float* __restrict__ br,
                                 unsigned short* __restrict__ xlb,
                                 unsigned short* __restrict__ xrb, int n) {
    __shared__ float hs[4][DIN];
    int node0 = blockIdx.x * 4;
    int tid = threadIdx.x;
    for (int idx = tid; idx < 4 * DIN; idx += 256) {
        int ln = idx / DIN, k = idx % DIN;
        int node = node0 + ln;
        hs[ln][k] = (node < n) ? h[(long long)node * DIN + k] : 0.f;
    }
    __syncthreads();
    int ln = tid >> 6;
    int j = tid & 63;
    int node = node0 + ln;
    if (node >= n) return;
    float al = bl[j], ar = br[j];
#pragma unroll 8
    for (int k = 0; k < DIN; ++k) {
        float hv = hs[ln][k];
        al += hv * Wl[k * 64 + j];
        ar += hv * Wr[k * 64 + j];
    }
    xlb[(long long)node * 64 + j] = f2bf(al);
    xrb[(long long)node * 64 + j] = f2bf(ar);
}

// ---------- phase A: MFMA edge scores, channel-permuted C layout ----------
__global__ __launch_bounds__(256, 2) void k_edge_score(
    const unsigned short* __restrict__ xlb, const unsigned short* __restrict__ xrb,
    const float* __restrict__ eattr,
    const float* __restrict__ We, const float* __restrict__ att,
    const int* __restrict__ src, const int* __restrict__ dst,
    const int* __restrict__ sortpos, int E,
    float* __restrict__ ex_sorted) {
    __shared__ __align__(16) short ea_frag[4][128][8];  // [k-chunk][edge][8 bf16] = 8 KB

    const int tid = threadIdx.x;
    const int ge0 = blockIdx.x * 128;
    const int w = tid >> 6, l = tid & 63;
    const int lo16 = l & 15, hi4 = l >> 4;

    // ---- early: edge ids + xl/xr gathers (latency hides under staging+MFMA) ----
    int sq[2], dq[2];
#pragma unroll
    for (int et = 0; et < 2; ++et) {
        int ge = ge0 + w * 32 + et * 16 + lo16;
        bool ok = ge < E;
        sq[et] = ok ? src[ge] : 0;
        dq[et] = ok ? dst[ge] : 0;
    }
    uint4 xlg[2][2], xrg[2][2];
#pragma unroll
    for (int et = 0; et < 2; ++et) {
        const size_t lbase = (size_t)sq[et] * 64 + hi4 * 16;
        const size_t rbase = (size_t)dq[et] * 64 + hi4 * 16;
        xlg[et][0] = *(const uint4*)&xlb[lbase];
        xlg[et][1] = *(const uint4*)&xlb[lbase + 8];
        xrg[et][0] = *(const uint4*)&xrb[rbase];
        xrg[et][1] = *(const uint4*)&xrb[rbase + 8];
    }

    // ---- stage ea -> bf16 B-fragments ----
    {
        const int e = tid & 127;
        const int c0 = (tid >> 7) * 2;
        const int ge = ge0 + e;
        float4 a = make_float4(0.f, 0.f, 0.f, 0.f), b = a, c = a, d4 = a;
        if (ge < E) {
            const float4* p = (const float4*)(eattr + (size_t)ge * 32 + c0 * 8);
            a = p[0]; b = p[1]; c = p[2]; d4 = p[3];
        }
        bf16x8 lo, hi;
        lo[0] = (short)f2bf(a.x); lo[1] = (short)f2bf(a.y); lo[2] = (short)f2bf(a.z); lo[3] = (short)f2bf(a.w);
        lo[4] = (short)f2bf(b.x); lo[5] = (short)f2bf(b.y); lo[6] = (short)f2bf(b.z); lo[7] = (short)f2bf(b.w);
        hi[0] = (short)f2bf(c.x); hi[1] = (short)f2bf(c.y); hi[2] = (short)f2bf(c.z); hi[3] = (short)f2bf(c.w);
        hi[4] = (short)f2bf(d4.x); hi[5] = (short)f2bf(d4.y); hi[6] = (short)f2bf(d4.z); hi[7] = (short)f2bf(d4.w);
        *(bf16x8*)&ea_frag[c0 + 0][e][0] = lo;
        *(bf16x8*)&ea_frag[c0 + 1][e][0] = hi;
    }

    // ---- A-fragments: permuted channel map ----
    bf16x8 afrag[4];
#pragma unroll
    for (int ct = 0; ct < 4; ++ct) {
        const int ch = (lo16 >> 2) * 16 + ct * 4 + (lo16 & 3);  // chmap(ct, lo16)
#pragma unroll
        for (int j = 0; j < 8; ++j) {
            afrag[ct][j] = (short)f2bf(We[(hi4 * 8 + j) * 64 + ch]);
        }
    }
    float attf[16];
    {
        const float4 a0 = *(const float4*)&att[hi4 * 16 + 0];
        const float4 a1 = *(const float4*)&att[hi4 * 16 + 4];
        const float4 a2 = *(const float4*)&att[hi4 * 16 + 8];
        const float4 a3 = *(const float4*)&att[hi4 * 16 + 12];
        attf[0] = a0.x;  attf[1] = a0.y;  attf[2] = a0.z;  attf[3] = a0.w;
        attf[4] = a1.x;  attf[5] = a1.y;  attf[6] = a1.z;  attf[7] = a1.w;
        attf[8] = a2.x;  attf[9] = a2.y;  attf[10] = a2.z; attf[11] = a2.w;
        attf[12] = a3.x; attf[13] = a3.y; attf[14] = a3.z; attf[15] = a3.w;
    }
    __syncthreads();

    // ---- MFMA: z[64ch x 32edges] per wave ----
    f32x4 acc[2][4];
#pragma unroll
    for (int et = 0; et < 2; ++et) {
        bf16x8 bfrag = *(const bf16x8*)&ea_frag[hi4][w * 32 + et * 16 + lo16][0];
#pragma unroll
        for (int ct = 0; ct < 4; ++ct) {
            f32x4 zero = {0.f, 0.f, 0.f, 0.f};
            acc[et][ct] = __builtin_amdgcn_mfma_f32_16x16x32_bf16(afrag[ct], bfrag, zero, 0, 0, 0);
        }
    }

    // ---- epilogue ----
#pragma unroll
    for (int et = 0; et < 2; ++et) {
        float xlf[16], xrf[16];
#pragma unroll
        for (int h = 0; h < 2; ++h) {
            const uint4 ql = xlg[et][h];
            const uint4 qr = xrg[et][h];
            xlf[h * 8 + 0] = bflo(ql.x); xlf[h * 8 + 1] = bfhi(ql.x);
            xlf[h * 8 + 2] = bflo(ql.y); xlf[h * 8 + 3] = bfhi(ql.y);
            xlf[h * 8 + 4] = bflo(ql.z); xlf[h * 8 + 5] = bfhi(ql.z);
            xlf[h * 8 + 6] = bflo(ql.w); xlf[h * 8 + 7] = bfhi(ql.w);
            xrf[h * 8 + 0] = bflo(qr.x); xrf[h * 8 + 1] = bfhi(qr.x);
            xrf[h * 8 + 2] = bflo(qr.y); xrf[h * 8 + 3] = bfhi(qr.y);
            xrf[h * 8 + 4] = bflo(qr.z); xrf[h * 8 + 5] = bfhi(qr.z);
            xrf[h * 8 + 6] = bflo(qr.w); xrf[h * 8 + 7] = bfhi(qr.w);
        }
        float part = 0.f;
#pragma unroll
        for (int ct = 0; ct < 4; ++ct) {
#pragma unroll
            for (int r = 0; r < 4; ++r) {
                const int i = ct * 4 + r;
                float zz = acc[et][ct][r] + xlf[i] + xrf[i];
                zz = (zz > 0.f) ? zz : NEG_SLOPE * zz;
                part += attf[i] * zz;
            }
        }
        part += __shfl_xor(part, 16);
        part += __shfl_xor(part, 32);
        if (l < 16) {
            int ge = ge0 + w * 32 + et * 16 + l;
            if (ge < E) ex_sorted[sortpos[ge]] = __expf(part);
        }
    }
}

// ---------- phase B: gather-side aggregation + in-kernel self-loop score ----------
template <bool FINAL>
__global__ __launch_bounds__(256, 2) void k_node_aggr(
    const unsigned short* __restrict__ xlb, const unsigned short* __restrict__ xrb,
    const float* __restrict__ loop_attr,
    const float* __restrict__ We, const float* __restrict__ att,
    const int* __restrict__ start,
    const int2* __restrict__ es_sorted, const float* __restrict__ ex_sorted,
    const float* __restrict__ bias,
    const float* __restrict__ Wc, const float* __restrict__ bc,
    float* __restrict__ hout, int n) {
    __shared__ float la_s[4][32];
    const int ln = threadIdx.x >> 6;
    const int node = blockIdx.x * 4 + ln;
    const int t = threadIdx.x & 63;

    if (threadIdx.x < 128) {
        int nn = blockIdx.x * 4 + (threadIdx.x >> 5);
        int k = threadIdx.x & 31;
        la_s[threadIdx.x >> 5][k] = (nn < n) ? loop_attr[(size_t)nn * 32 + k] : 0.f;
    }
    __syncthreads();
    if (node >= n) return;

    float exl;
    {
        float zl = bf2f(xlb[(size_t)node * 64 + t]) + bf2f(xrb[(size_t)node * 64 + t]);
#pragma unroll 8
        for (int k = 0; k < 32; ++k) zl += We[k * 64 + t] * la_s[ln][k];
        zl = (zl > 0.f) ? zl : NEG_SLOPE * zl;
        float v = att[t] * zl;
#pragma unroll
        for (int mask = 1; mask <= 32; mask <<= 1) v += __shfl_xor(v, mask);
        exl = __expf(v);
    }

    const int g = t >> 3;
    const int c8 = t & 7;
    int a = start[node], b = start[node + 1];

    float acc[8] = {0.f, 0.f, 0.f, 0.f, 0.f, 0.f, 0.f, 0.f};
    float den = 0.f;
    if (g == 0) {
        const uint4 q = *(const uint4*)&xlb[(size_t)node * 64 + c8 * 8];
        acc[0] = exl * bflo(q.x); acc[1] = exl * bfhi(q.x);
        acc[2] = exl * bflo(q.y); acc[3] = exl * bfhi(q.y);
        acc[4] = exl * bflo(q.z); acc[5] = exl * bfhi(q.z);
        acc[6] = exl * bflo(q.w); acc[7] = exl * bfhi(q.w);
        den = exl;
    }
    for (int j = a; j < b; j += 64) {
        int m = b - j; if (m > 64) m = 64;
        int sj = 0; float exj = 0.f;
        if (t < m) { sj = es_sorted[j + t].y; exj = ex_sorted[j + t]; }
        for (int i = 0; i < m; i += 16) {
            const int i0 = i + g, i1 = i + 8 + g;
            const int s0 = __shfl(sj, i0); const float e0 = __shfl(exj, i0);
            const int s1 = __shfl(sj, i1); const float e1 = __shfl(exj, i1);
            uint4 q0 = *(const uint4*)&xlb[(size_t)s0 * 64 + c8 * 8];
            uint4 q1 = *(const uint4*)&xlb[(size_t)s1 * 64 + c8 * 8];
            if (i0 < m) {
                acc[0] += e0 * bflo(q0.x); acc[1] += e0 * bfhi(q0.x);
                acc[2] += e0 * bflo(q0.y); acc[3] += e0 * bfhi(q0.y);
                acc[4] += e0 * bflo(q0.z); acc[5] += e0 * bfhi(q0.z);
                acc[6] += e0 * bflo(q0.w); acc[7] += e0 * bfhi(q0.w);
                den += e0;
            }
            if (i1 < m) {
                acc[0] += e1 * bflo(q1.x); acc[1] += e1 * bfhi(q1.x);
                acc[2] += e1 * bflo(q1.y); acc[3] += e1 * bfhi(q1.y);
                acc[4] += e1 * bflo(q1.z); acc[5] += e1 * bfhi(q1.z);
                acc[6] += e1 * bflo(q1.w); acc[7] += e1 * bfhi(q1.w);
                den += e1;
            }
        }
    }
#pragma unroll
    for (int mask = 8; mask <= 32; mask <<= 1) {
#pragma unroll
        for (int r = 0; r < 8; ++r) acc[r] += __shfl_xor(acc[r], mask);
        den += __shfl_xor(den, mask);
    }
    if (!FINAL) {
        if (g == 0) {
            float h[8];
#pragma unroll
            for (int r = 0; r < 8; ++r)
                h[r] = fmaxf(acc[r] / den + bias[c8 * 8 + r], 0.f);
            float4 o0 = make_float4(h[0], h[1], h[2], h[3]);
            float4 o1 = make_float4(h[4], h[5], h[6], h[7]);
            *(float4*)&hout[(size_t)node * 64 + c8 * 8] = o0;
            *(float4*)&hout[(size_t)node * 64 + c8 * 8 + 4] = o1;
        }
    } else {
        float v0 = 0.f, v1 = 0.f;
        if (g == 0) {
#pragma unroll
            for (int r = 0; r < 8; ++r) {
                const int ch = c8 * 8 + r;
                const float h = fmaxf(acc[r] / den + bias[ch], 0.f);
                v0 += h * Wc[ch * 2 + 0];
                v1 += h * Wc[ch * 2 + 1];
            }
        }
#pragma unroll
        for (int mask = 1; mask <= 4; mask <<= 1) {
            v0 += __shfl_xor(v0, mask);
            v1 += __shfl_xor(v1, mask);
        }
        if (t == 0) {
            hout[(size_t)node * 2 + 0] = v0 + bc[0];
            hout[(size_t)node * 2 + 1] = v1 + bc[1];
        }
    }
}

extern "C" void kernel_launch(void* const* d_in, const int* in_sizes, int n_in,
                              void* d_out, int out_size, void* d_ws, size_t ws_size,
                              hipStream_t stream) {
    const float* x     = (const float*)d_in[0];
    const int*   ei    = (const int*)d_in[1];
    const float* eattr = (const float*)d_in[2];
    const float* Wl1 = (const float*)d_in[3];
    const float* bl1 = (const float*)d_in[4];
    const float* Wr1 = (const float*)d_in[5];
    const float* br1 = (const float*)d_in[6];
    const float* We1 = (const float*)d_in[7];
    const float* att1 = (const float*)d_in[8];
    const float* bias1 = (const float*)d_in[9];
    const float* Wl2 = (const float*)d_in[10];
    const float* bl2 = (const float*)d_in[11];
    const float* Wr2 = (const float*)d_in[12];
    const float* br2 = (const float*)d_in[13];
    const float* We2 = (const float*)d_in[14];
    const float* att2 = (const float*)d_in[15];
    const float* bias2 = (const float*)d_in[16];
    const float* Wc = (const float*)d_in[17];
    const float* bc = (const float*)d_in[18];

    const int N = in_sizes[0] / 128;
    const int E = in_sizes[1] / 2;
    const int* src = ei;
    const int* dst = ei + E;

    char* w = (char*)d_ws;
    auto alloc = [&](size_t bytes) {
        char* p = w;
        w += (bytes + 255) & ~(size_t)255;
        return p;
    };
    unsigned short* xlb        = (unsigned short*)alloc((size_t)N * 64 * 2);
    unsigned short* xrb        = (unsigned short*)alloc((size_t)N * 64 * 2);
    float*          hbuf       = (float*)alloc((size_t)N * 64 * 4);
    float*          loop_attr  = (float*)alloc((size_t)N * 32 * 4);
    int*            deg_i      = (int*)alloc((size_t)N * 4);
    int*            start      = (int*)alloc((size_t)(N + 1) * 4);
    int*            cursor     = (int*)alloc((size_t)N * 4);
    int*            csum       = (int*)alloc(256 * 4);
    int2*           es_sorted  = (int2*)alloc((size_t)E * 8);
    int*            sortpos    = (int*)alloc((size_t)E * 4);
    float*          ex_sorted  = (float*)alloc((size_t)E * 4);

    const int THREADS = 256;
    const int score_blocks = (E + 127) / 128;
    const int node4_blocks = (N + 3) / 4;
    const int edge_blocks = (E + THREADS - 1) / THREADS;
    const int nchunks = (N + 1023) / 1024;

    // ---- CSR by dst (shared by both layers) ----
    hipMemsetAsync(deg_i, 0, (size_t)N * 4, stream);
    hipMemsetAsync(cursor, 0, (size_t)N * 4, stream);
    k_hist<<<edge_blocks, THREADS, 0, stream>>>(dst, E, deg_i);
    k_scan_chunk<<<nchunks, 1024, 0, stream>>>(deg_i, start, csum, N);
    k_scan_top<<<1, 64, 0, stream>>>(csum, nchunks, start, N);
    k_scan_apply<<<(N + THREADS - 1) / THREADS, THREADS, 0, stream>>>(start, csum, N);
    k_fill<<<edge_blocks, THREADS, 0, stream>>>(src, dst, E, start, cursor,
                                                es_sorted, sortpos);
    k_loop_csr<<<node4_blocks, THREADS, 0, stream>>>(eattr, es_sorted, start, loop_attr, N);

    // ---- layer 1 ----
    k_node_transform<128><<<node4_blocks, THREADS, 0, stream>>>(x, Wl1, bl1, Wr1, br1,
                                                                xlb, xrb, N);
    k_edge_score<<<score_blocks, THREADS, 0, stream>>>(
        xlb, xrb, eattr, We1, att1, src, dst, sortpos, E, ex_sorted);
    k_node_aggr<false><<<node4_blocks, THREADS, 0, stream>>>(
        xlb, xrb, loop_attr, We1, att1, start, es_sorted, ex_sorted,
        bias1, Wc, bc, hbuf, N);

    // ---- layer 2 ----
    k_node_transform<64><<<node4_blocks, THREADS, 0, stream>>>(hbuf, Wl2, bl2, Wr2, br2,
                                                               xlb, xrb, N);
    k_edge_score<<<score_blocks, THREADS, 0, stream>>>(
        xlb, xrb, eattr, We2, att2, src, dst, sortpos, E, ex_sorted);
    k_node_aggr<true><<<node4_blocks, THREADS, 0, stream>>>(
        xlb, xrb, loop_attr, We2, att2, start, es_sorted, ex_sorted,
        bias2, Wc, bc, (float*)d_out, N);
}

// Round 17
// 631.093 us; speedup vs baseline: 1.1903x; 1.1428x over previous
//
#include <hip/hip_runtime.h>
#include <hip/hip_bf16.h>

#define NEG_SLOPE 0.2f

typedef __attribute__((ext_vector_type(8))) short bf16x8;
typedef __attribute__((ext_vector_type(4))) float f32x4;

__device__ __forceinline__ float bf2f(unsigned short u) {
    return __uint_as_float((unsigned)u << 16);
}
__device__ __forceinline__ float bflo(unsigned u) { return __uint_as_float(u << 16); }
__device__ __forceinline__ float bfhi(unsigned u) { return __uint_as_float(u & 0xFFFF0000u); }
__device__ __forceinline__ unsigned short f2bf(float f) {
    unsigned b = __float_as_uint(f);
    return (unsigned short)((b + 0x7FFFu + ((b >> 16) & 1u)) >> 16);
}
__device__ __forceinline__ unsigned pack2(float lo, float hi) {
    return (unsigned)f2bf(lo) | ((unsigned)f2bf(hi) << 16);
}

// ---------- CSR build ----------
__global__ void k_hist(const int* __restrict__ dst, int E, int* __restrict__ deg) {
    int e = blockIdx.x * 256 + threadIdx.x;
    if (e < E) atomicAdd(&deg[dst[e]], 1);
}

__global__ __launch_bounds__(1024) void k_scan_chunk(const int* __restrict__ deg,
                                                     int* __restrict__ start,
                                                     int* __restrict__ csum, int n) {
    __shared__ int wsum[16];
    const int lane = threadIdx.x & 63;
    const int w = threadIdx.x >> 6;
    int i = blockIdx.x * 1024 + (int)threadIdx.x;
    int v = (i < n) ? deg[i] : 0;
    int s = v;
#pragma unroll
    for (int o = 1; o < 64; o <<= 1) {
        int u = __shfl_up(s, o);
        if (lane >= o) s += u;
    }
    if (lane == 63) wsum[w] = s;
    __syncthreads();
    if (w == 0) {
        int ws = (lane < 16) ? wsum[lane] : 0;
#pragma unroll
        for (int o = 1; o < 16; o <<= 1) {
            int u = __shfl_up(ws, o);
            if (lane >= o) ws += u;
        }
        if (lane < 16) wsum[lane] = ws;
    }
    __syncthreads();
    int woff = (w == 0) ? 0 : wsum[w - 1];
    int incl = s + woff;
    if (i < n) start[i] = incl - v;
    if (threadIdx.x == 1023) csum[blockIdx.x] = incl;
}

__global__ void k_scan_top(int* __restrict__ csum, int nch, int* __restrict__ start, int n) {
    int t = threadIdx.x;
    int v = (t < nch) ? csum[t] : 0;
    int s = v;
#pragma unroll
    for (int o = 1; o < 64; o <<= 1) {
        int u = __shfl_up(s, o);
        if (t >= o) s += u;
    }
    if (t < nch) csum[t] = s - v;
    if (t == 63) start[n] = s;
}

__global__ void k_scan_apply(int* __restrict__ start, const int* __restrict__ csum, int n) {
    int i = blockIdx.x * 256 + threadIdx.x;
    if (i < n) start[i] += csum[i >> 10];
}

// fill: one 8B scatter {src,dst} + one 64B bf16 eattr-row scatter per edge.
// eattr_s[idx] is exactly one cache line -> minimal dirty-line traffic.
__global__ void k_fill(const float* __restrict__ eattr,
                       const int* __restrict__ src, const int* __restrict__ dst, int E,
                       const int* __restrict__ start, int* __restrict__ cursor,
                       int2* __restrict__ sd_sorted, unsigned short* __restrict__ eattr_s) {
    int e = blockIdx.x * 256 + threadIdx.x;
    if (e >= E) return;
    int d = dst[e];
    int idx = start[d] + atomicAdd(&cursor[d], 1);
    sd_sorted[idx] = make_int2(src[e], d);
    const float4* p = (const float4*)(eattr + (size_t)e * 32);
    uint4* q = (uint4*)(eattr_s + (size_t)idx * 32);
#pragma unroll
    for (int c = 0; c < 4; ++c) {
        const float4 a = p[2 * c], b = p[2 * c + 1];
        uint4 o;
        o.x = pack2(a.x, a.y); o.y = pack2(a.z, a.w);
        o.z = pack2(b.x, b.y); o.w = pack2(b.z, b.w);
        q[c] = o;
    }
}

// ---------- self-loop attr: STREAMING segment mean over sorted bf16 rows ----------
// wave per node; lanes 0..15 cover one 64B row (channel pairs), 4 rows/iter.
__global__ __launch_bounds__(256) void k_loop_csr(
    const unsigned short* __restrict__ eattr_s, const int* __restrict__ start,
    float* __restrict__ loop_attr, int n) {
    int node = blockIdx.x * 4 + (threadIdx.x >> 6);
    int t = threadIdx.x & 63;
    if (node >= n) return;
    int a = start[node], b = start[node + 1];
    const int rpi = t >> 4;   // row-in-group 0..3
    const int cp = t & 15;    // channel pair
    float ax = 0.f, ay = 0.f;
    for (int j = a + rpi; j < b; j += 4) {
        unsigned u = *(const unsigned*)&eattr_s[(size_t)j * 32 + cp * 2];
        ax += bflo(u); ay += bfhi(u);
    }
#pragma unroll
    for (int mask = 16; mask <= 32; mask <<= 1) {
        ax += __shfl_xor(ax, mask);
        ay += __shfl_xor(ay, mask);
    }
    if (t < 16) {
        float deg = fmaxf((float)(b - a), 1.f);
        float2 o = make_float2(ax / deg, ay / deg);
        *(float2*)&loop_attr[(size_t)node * 32 + cp * 2] = o;
    }
}

// ---------- node transform: bf16 tables only ----------
template <int DIN>
__global__ void k_node_transform(const float* __restrict__ h,
                                 const float* __restrict__ Wl, const float* __restrict__ bl,
                                 const float* __restrict__ Wr, const float* __restrict__ br,
                                 unsigned short* __restrict__ xlb,
                                 unsigned short* __restrict__ xrb, int n) {
    __shared__ float hs[4][DIN];
    int node0 = blockIdx.x * 4;
    int tid = threadIdx.x;
    for (int idx = tid; idx < 4 * DIN; idx += 256) {
        int ln = idx / DIN, k = idx % DIN;
        int node = node0 + ln;
        hs[ln][k] = (node < n) ? h[(long long)node * DIN + k] : 0.f;
    }
    __syncthreads();
    int ln = tid >> 6;
    int j = tid & 63;
    int node = node0 + ln;
    if (node >= n) return;
    float al = bl[j], ar = br[j];
#pragma unroll 8
    for (int k = 0; k < DIN; ++k) {
        float hv = hs[ln][k];
        al += hv * Wl[k * 64 + j];
        ar += hv * Wr[k * 64 + j];
    }
    xlb[(long long)node * 64 + j] = f2bf(al);
    xrb[(long long)node * 64 + j] = f2bf(ar);
}

// ---------- phase A: MFMA edge scores over SORTED edges ----------
// 128 edges/block; eattr_s rows are pre-converted bf16 in sorted order ->
// staging is 2 uint4 copies; xr[dst] gathers have run-length L1 locality;
// ex writes coalesced. Channel-permuted C layout as R15/R16 (verified).
__global__ __launch_bounds__(256, 2) void k_edge_score(
    const unsigned short* __restrict__ xlb, const unsigned short* __restrict__ xrb,
    const unsigned short* __restrict__ eattr_s,
    const float* __restrict__ We, const float* __restrict__ att,
    const int2* __restrict__ sd_sorted, int E,
    float* __restrict__ ex_sorted) {
    __shared__ __align__(16) short ea_frag[4][128][8];  // 8 KB

    const int tid = threadIdx.x;
    const int ge0 = blockIdx.x * 128;
    const int w = tid >> 6, l = tid & 63;
    const int lo16 = l & 15, hi4 = l >> 4;

    // ---- early: edge ids + xl/xr gathers ----
    int2 sd[2];
#pragma unroll
    for (int et = 0; et < 2; ++et) {
        int ge = ge0 + w * 32 + et * 16 + lo16;
        sd[et] = (ge < E) ? sd_sorted[ge] : make_int2(0, 0);
    }
    uint4 xlg[2][2], xrg[2][2];
#pragma unroll
    for (int et = 0; et < 2; ++et) {
        const size_t lbase = (size_t)sd[et].x * 64 + hi4 * 16;
        const size_t rbase = (size_t)sd[et].y * 64 + hi4 * 16;
        xlg[et][0] = *(const uint4*)&xlb[lbase];
        xlg[et][1] = *(const uint4*)&xlb[lbase + 8];
        xrg[et][0] = *(const uint4*)&xrb[rbase];
        xrg[et][1] = *(const uint4*)&xrb[rbase + 8];
    }

    // ---- stage ea: direct bf16 copies (2 threads/edge, 32B each) ----
    {
        const int e = tid & 127;
        const int c0 = (tid >> 7) * 2;
        const int ge = ge0 + e;
        uint4 q0 = make_uint4(0, 0, 0, 0), q1 = q0;
        if (ge < E) {
            const uint4* p = (const uint4*)(eattr_s + (size_t)ge * 32 + c0 * 8);
            q0 = p[0]; q1 = p[1];
        }
        *(uint4*)&ea_frag[c0 + 0][e][0] = q0;
        *(uint4*)&ea_frag[c0 + 1][e][0] = q1;
    }

    // ---- A-fragments: permuted channel map ----
    bf16x8 afrag[4];
#pragma unroll
    for (int ct = 0; ct < 4; ++ct) {
        const int ch = (lo16 >> 2) * 16 + ct * 4 + (lo16 & 3);  // chmap(ct, lo16)
#pragma unroll
        for (int j = 0; j < 8; ++j) {
            afrag[ct][j] = (short)f2bf(We[(hi4 * 8 + j) * 64 + ch]);
        }
    }
    float attf[16];
    {
        const float4 a0 = *(const float4*)&att[hi4 * 16 + 0];
        const float4 a1 = *(const float4*)&att[hi4 * 16 + 4];
        const float4 a2 = *(const float4*)&att[hi4 * 16 + 8];
        const float4 a3 = *(const float4*)&att[hi4 * 16 + 12];
        attf[0] = a0.x;  attf[1] = a0.y;  attf[2] = a0.z;  attf[3] = a0.w;
        attf[4] = a1.x;  attf[5] = a1.y;  attf[6] = a1.z;  attf[7] = a1.w;
        attf[8] = a2.x;  attf[9] = a2.y;  attf[10] = a2.z; attf[11] = a2.w;
        attf[12] = a3.x; attf[13] = a3.y; attf[14] = a3.z; attf[15] = a3.w;
    }
    __syncthreads();

    // ---- MFMA: z[64ch x 32edges] per wave ----
    f32x4 acc[2][4];
#pragma unroll
    for (int et = 0; et < 2; ++et) {
        bf16x8 bfrag = *(const bf16x8*)&ea_frag[hi4][w * 32 + et * 16 + lo16][0];
#pragma unroll
        for (int ct = 0; ct < 4; ++ct) {
            f32x4 zero = {0.f, 0.f, 0.f, 0.f};
            acc[et][ct] = __builtin_amdgcn_mfma_f32_16x16x32_bf16(afrag[ct], bfrag, zero, 0, 0, 0);
        }
    }

    // ---- epilogue ----
#pragma unroll
    for (int et = 0; et < 2; ++et) {
        float xlf[16], xrf[16];
#pragma unroll
        for (int h = 0; h < 2; ++h) {
            const uint4 ql = xlg[et][h];
            const uint4 qr = xrg[et][h];
            xlf[h * 8 + 0] = bflo(ql.x); xlf[h * 8 + 1] = bfhi(ql.x);
            xlf[h * 8 + 2] = bflo(ql.y); xlf[h * 8 + 3] = bfhi(ql.y);
            xlf[h * 8 + 4] = bflo(ql.z); xlf[h * 8 + 5] = bfhi(ql.z);
            xlf[h * 8 + 6] = bflo(ql.w); xlf[h * 8 + 7] = bfhi(ql.w);
            xrf[h * 8 + 0] = bflo(qr.x); xrf[h * 8 + 1] = bfhi(qr.x);
            xrf[h * 8 + 2] = bflo(qr.y); xrf[h * 8 + 3] = bfhi(qr.y);
            xrf[h * 8 + 4] = bflo(qr.z); xrf[h * 8 + 5] = bfhi(qr.z);
            xrf[h * 8 + 6] = bflo(qr.w); xrf[h * 8 + 7] = bfhi(qr.w);
        }
        float part = 0.f;
#pragma unroll
        for (int ct = 0; ct < 4; ++ct) {
#pragma unroll
            for (int r = 0; r < 4; ++r) {
                const int i = ct * 4 + r;
                float zz = acc[et][ct][r] + xlf[i] + xrf[i];
                zz = (zz > 0.f) ? zz : NEG_SLOPE * zz;
                part += attf[i] * zz;
            }
        }
        part += __shfl_xor(part, 16);
        part += __shfl_xor(part, 32);
        if (l < 16) {
            int ge = ge0 + w * 32 + et * 16 + l;
            if (ge < E) ex_sorted[ge] = __expf(part);
        }
    }
}

// ---------- phase B: gather-side aggregation + in-kernel self-loop score ----------
template <bool FINAL>
__global__ __launch_bounds__(256, 2) void k_node_aggr(
    const unsigned short* __restrict__ xlb, const unsigned short* __restrict__ xrb,
    const float* __restrict__ loop_attr,
    const float* __restrict__ We, const float* __restrict__ att,
    const int* __restrict__ start,
    const int2* __restrict__ sd_sorted, const float* __restrict__ ex_sorted,
    const float* __restrict__ bias,
    const float* __restrict__ Wc, const float* __restrict__ bc,
    float* __restrict__ hout, int n) {
    __shared__ float la_s[4][32];
    const int ln = threadIdx.x >> 6;
    const int node = blockIdx.x * 4 + ln;
    const int t = threadIdx.x & 63;

    if (threadIdx.x < 128) {
        int nn = blockIdx.x * 4 + (threadIdx.x >> 5);
        int k = threadIdx.x & 31;
        la_s[threadIdx.x >> 5][k] = (nn < n) ? loop_attr[(size_t)nn * 32 + k] : 0.f;
    }
    __syncthreads();
    if (node >= n) return;

    float exl;
    {
        float zl = bf2f(xlb[(size_t)node * 64 + t]) + bf2f(xrb[(size_t)node * 64 + t]);
#pragma unroll 8
        for (int k = 0; k < 32; ++k) zl += We[k * 64 + t] * la_s[ln][k];
        zl = (zl > 0.f) ? zl : NEG_SLOPE * zl;
        float v = att[t] * zl;
#pragma unroll
        for (int mask = 1; mask <= 32; mask <<= 1) v += __shfl_xor(v, mask);
        exl = __expf(v);
    }

    const int g = t >> 3;
    const int c8 = t & 7;
    int a = start[node], b = start[node + 1];

    float acc[8] = {0.f, 0.f, 0.f, 0.f, 0.f, 0.f, 0.f, 0.f};
    float den = 0.f;
    if (g == 0) {
        const uint4 q = *(const uint4*)&xlb[(size_t)node * 64 + c8 * 8];
        acc[0] = exl * bflo(q.x); acc[1] = exl * bfhi(q.x);
        acc[2] = exl * bflo(q.y); acc[3] = exl * bfhi(q.y);
        acc[4] = exl * bflo(q.z); acc[5] = exl * bfhi(q.z);
        acc[6] = exl * bflo(q.w); acc[7] = exl * bfhi(q.w);
        den = exl;
    }
    for (int j = a; j < b; j += 64) {
        int m = b - j; if (m > 64) m = 64;
        int sj = 0; float exj = 0.f;
        if (t < m) { sj = sd_sorted[j + t].x; exj = ex_sorted[j + t]; }
        for (int i = 0; i < m; i += 16) {
            const int i0 = i + g, i1 = i + 8 + g;
            const int s0 = __shfl(sj, i0); const float e0 = __shfl(exj, i0);
            const int s1 = __shfl(sj, i1); const float e1 = __shfl(exj, i1);
            uint4 q0 = *(const uint4*)&xlb[(size_t)s0 * 64 + c8 * 8];
            uint4 q1 = *(const uint4*)&xlb[(size_t)s1 * 64 + c8 * 8];
            if (i0 < m) {
                acc[0] += e0 * bflo(q0.x); acc[1] += e0 * bfhi(q0.x);
                acc[2] += e0 * bflo(q0.y); acc[3] += e0 * bfhi(q0.y);
                acc[4] += e0 * bflo(q0.z); acc[5] += e0 * bfhi(q0.z);
                acc[6] += e0 * bflo(q0.w); acc[7] += e0 * bfhi(q0.w);
                den += e0;
            }
            if (i1 < m) {
                acc[0] += e1 * bflo(q1.x); acc[1] += e1 * bfhi(q1.x);
                acc[2] += e1 * bflo(q1.y); acc[3] += e1 * bfhi(q1.y);
                acc[4] += e1 * bflo(q1.z); acc[5] += e1 * bfhi(q1.z);
                acc[6] += e1 * bflo(q1.w); acc[7] += e1 * bfhi(q1.w);
                den += e1;
            }
        }
    }
#pragma unroll
    for (int mask = 8; mask <= 32; mask <<= 1) {
#pragma unroll
        for (int r = 0; r < 8; ++r) acc[r] += __shfl_xor(acc[r], mask);
        den += __shfl_xor(den, mask);
    }
    if (!FINAL) {
        if (g == 0) {
            float h[8];
#pragma unroll
            for (int r = 0; r < 8; ++r)
                h[r] = fmaxf(acc[r] / den + bias[c8 * 8 + r], 0.f);
            float4 o0 = make_float4(h[0], h[1], h[2], h[3]);
            float4 o1 = make_float4(h[4], h[5], h[6], h[7]);
            *(float4*)&hout[(size_t)node * 64 + c8 * 8] = o0;
            *(float4*)&hout[(size_t)node * 64 + c8 * 8 + 4] = o1;
        }
    } else {
        float v0 = 0.f, v1 = 0.f;
        if (g == 0) {
#pragma unroll
            for (int r = 0; r < 8; ++r) {
                const int ch = c8 * 8 + r;
                const float h = fmaxf(acc[r] / den + bias[ch], 0.f);
                v0 += h * Wc[ch * 2 + 0];
                v1 += h * Wc[ch * 2 + 1];
            }
        }
#pragma unroll
        for (int mask = 1; mask <= 4; mask <<= 1) {
            v0 += __shfl_xor(v0, mask);
            v1 += __shfl_xor(v1, mask);
        }
        if (t == 0) {
            hout[(size_t)node * 2 + 0] = v0 + bc[0];
            hout[(size_t)node * 2 + 1] = v1 + bc[1];
        }
    }
}

extern "C" void kernel_launch(void* const* d_in, const int* in_sizes, int n_in,
                              void* d_out, int out_size, void* d_ws, size_t ws_size,
                              hipStream_t stream) {
    const float* x     = (const float*)d_in[0];
    const int*   ei    = (const int*)d_in[1];
    const float* eattr = (const float*)d_in[2];
    const float* Wl1 = (const float*)d_in[3];
    const float* bl1 = (const float*)d_in[4];
    const float* Wr1 = (const float*)d_in[5];
    const float* br1 = (const float*)d_in[6];
    const float* We1 = (const float*)d_in[7];
    const float* att1 = (const float*)d_in[8];
    const float* bias1 = (const float*)d_in[9];
    const float* Wl2 = (const float*)d_in[10];
    const float* bl2 = (const float*)d_in[11];
    const float* Wr2 = (const float*)d_in[12];
    const float* br2 = (const float*)d_in[13];
    const float* We2 = (const float*)d_in[14];
    const float* att2 = (const float*)d_in[15];
    const float* bias2 = (const float*)d_in[16];
    const float* Wc = (const float*)d_in[17];
    const float* bc = (const float*)d_in[18];

    const int N = in_sizes[0] / 128;
    const int E = in_sizes[1] / 2;
    const int* src = ei;
    const int* dst = ei + E;

    char* w = (char*)d_ws;
    auto alloc = [&](size_t bytes) {
        char* p = w;
        w += (bytes + 255) & ~(size_t)255;
        return p;
    };
    unsigned short* xlb        = (unsigned short*)alloc((size_t)N * 64 * 2);
    unsigned short* xrb        = (unsigned short*)alloc((size_t)N * 64 * 2);
    float*          hbuf       = (float*)alloc((size_t)N * 64 * 4);
    float*          loop_attr  = (float*)alloc((size_t)N * 32 * 4);
    int*            deg_i      = (int*)alloc((size_t)N * 4);
    int*            start      = (int*)alloc((size_t)(N + 1) * 4);
    int*            cursor     = (int*)alloc((size_t)N * 4);
    int*            csum       = (int*)alloc(256 * 4);
    int2*           sd_sorted  = (int2*)alloc((size_t)E * 8);
    float*          ex_sorted  = (float*)alloc((size_t)E * 4);
    unsigned short* eattr_s    = (unsigned short*)alloc((size_t)E * 32 * 2);

    const int THREADS = 256;
    const int score_blocks = (E + 127) / 128;
    const int node4_blocks = (N + 3) / 4;
    const int edge_blocks = (E + THREADS - 1) / THREADS;
    const int nchunks = (N + 1023) / 1024;

    // ---- CSR by dst + sorted bf16 eattr copy (shared by both layers) ----
    hipMemsetAsync(deg_i, 0, (size_t)N * 4, stream);
    hipMemsetAsync(cursor, 0, (size_t)N * 4, stream);
    k_hist<<<edge_blocks, THREADS, 0, stream>>>(dst, E, deg_i);
    k_scan_chunk<<<nchunks, 1024, 0, stream>>>(deg_i, start, csum, N);
    k_scan_top<<<1, 64, 0, stream>>>(csum, nchunks, start, N);
    k_scan_apply<<<(N + THREADS - 1) / THREADS, THREADS, 0, stream>>>(start, csum, N);
    k_fill<<<edge_blocks, THREADS, 0, stream>>>(eattr, src, dst, E, start, cursor,
                                                sd_sorted, eattr_s);
    k_loop_csr<<<node4_blocks, THREADS, 0, stream>>>(eattr_s, start, loop_attr, N);

    // ---- layer 1 ----
    k_node_transform<128><<<node4_blocks, THREADS, 0, stream>>>(x, Wl1, bl1, Wr1, br1,
                                                                xlb, xrb, N);
    k_edge_score<<<score_blocks, THREADS, 0, stream>>>(
        xlb, xrb, eattr_s, We1, att1, sd_sorted, E, ex_sorted);
    k_node_aggr<false><<<node4_blocks, THREADS, 0, stream>>>(
        xlb, xrb, loop_attr, We1, att1, start, sd_sorted, ex_sorted,
        bias1, Wc, bc, hbuf, N);

    // ---- layer 2 ----
    k_node_transform<64><<<node4_blocks, THREADS, 0, stream>>>(hbuf, Wl2, bl2, Wr2, br2,
                                                               xlb, xrb, N);
    k_edge_score<<<score_blocks, THREADS, 0, stream>>>(
        xlb, xrb, eattr_s, We2, att2, sd_sorted, E, ex_sorted);
    k_node_aggr<true><<<node4_blocks, THREADS, 0, stream>>>(
        xlb, xrb, loop_attr, We2, att2, start, sd_sorted, ex_sorted,
        bias2, Wc, bc, (float*)d_out, N);
}